// Round 2
// baseline (3223.236 us; speedup 1.0000x reference)
//
#include <hip/hip_runtime.h>
#include <cstdint>
#include <cstddef>

#define NROWS    262144
#define DIN      512
#define H1DIM    1024
#define H2DIM    1024
#define DOUT     512
#define MASKN    134217728ull
#define CHUNK    65536

typedef __bf16 bf16x8 __attribute__((ext_vector_type(8)));
typedef float  f32x4  __attribute__((ext_vector_type(4)));
typedef unsigned short u16;
typedef u16 u16x8 __attribute__((ext_vector_type(8)));

__device__ __forceinline__ u16 f2bf(float f) {
  union { float f; uint32_t u; } v; v.f = f;
  uint32_t r = v.u + 0x7FFFu + ((v.u >> 16) & 1u);   // RNE; inputs finite, no NaN path
  return (u16)(r >> 16);
}

__device__ __forceinline__ void gload_lds16(const void* g, void* l) {
  __builtin_amdgcn_global_load_lds(
      (const __attribute__((address_space(1))) uint32_t*)g,
      (__attribute__((address_space(3))) uint32_t*)l,
      16, 0, 0);   // width=16: global_load_lds_dwordx4
}

// Bijective XCD swizzle (m204): hardware round-robins blockIdx across 8 XCDs;
// remap so each XCD owns a CONTIGUOUS run of tiles -> A-panel reuse is L2-local.
__device__ __forceinline__ int xcd_swizzle(int bid, int nwg) {
  const int nx = 8;
  const int q = nwg / nx, r = nwg % nx;
  const int xcd = bid % nx, lid = bid / nx;
  return (xcd < r ? xcd * (q + 1) : r * (q + 1) + (xcd - r) * q) + lid;
}

// C[m,n] = relu( sum_k A[m,k]*B[n,k] + bias[n] )
// A: [M x K] bf16 row-major, B: [N x K] bf16 row-major (torch weight layout)
// EPI==0: store bf16 to Cout ([M x N]); EPI==1: store fp32 + atomic global sum
template<int EPI>
__global__ __launch_bounds__(256, 2)
void mlp_gemm(const u16* __restrict__ A, const u16* __restrict__ B,
              const float* __restrict__ bias, void* __restrict__ Cout,
              float* __restrict__ sum_acc, int M, int N, int K)
{
  __shared__ __align__(16) u16 As[128 * 64];
  __shared__ __align__(16) u16 Bs[128 * 64];
  const int tid  = threadIdx.x;
  const int wid  = tid >> 6;
  const int lane = tid & 63;
  const int l15  = lane & 15;
  const int l4   = lane >> 4;
  const int nbn  = N >> 7;
  const int swz  = xcd_swizzle(blockIdx.x, gridDim.x);
  const int bm   = swz / nbn;
  const int bn   = swz % nbn;
  const int m0 = bm << 7, n0 = bn << 7;

  f32x4 acc[4][4] = {};

  const int ar = (wid >> 1) * 64;   // wave row offset in tile
  const int ac = (wid & 1) * 64;    // wave col offset in tile

  for (int k0 = 0; k0 < K; k0 += 64) {
    // ---- stage A[128x64], B[128x64] via global_load_lds (linear LDS dest) ----
    #pragma unroll
    for (int i = 0; i < 4; ++i) {
      const int c = i * 256 + tid;            // 16B chunk id, 8 chunks per row
      const int row = c >> 3, col = (c & 7) << 3;
      gload_lds16(A + (size_t)(m0 + row) * K + (size_t)(k0 + col),
                  &As[(size_t)(i * 256 + wid * 64) * 8]);  // wave-uniform base + lane*16
    }
    #pragma unroll
    for (int i = 0; i < 4; ++i) {
      const int c = i * 256 + tid;
      const int row = c >> 3, col = (c & 7) << 3;
      gload_lds16(B + (size_t)(n0 + row) * K + (size_t)(k0 + col),
                  &Bs[(size_t)(i * 256 + wid * 64) * 8]);
    }
    __syncthreads();   // compiler emits vmcnt(0) drain before s_barrier

    // ---- compute: 2 K-chunks of 32, 16 MFMA each ----
    #pragma unroll
    for (int kk = 0; kk < 64; kk += 32) {
      bf16x8 af[4], bfr[4];
      #pragma unroll
      for (int m = 0; m < 4; ++m)
        af[m] = *(const bf16x8*)&As[(ar + m * 16 + l15) * 64 + kk + l4 * 8];
      #pragma unroll
      for (int n = 0; n < 4; ++n)
        bfr[n] = *(const bf16x8*)&Bs[(ac + n * 16 + l15) * 64 + kk + l4 * 8];
      #pragma unroll
      for (int m = 0; m < 4; ++m)
        #pragma unroll
        for (int n = 0; n < 4; ++n)
          acc[m][n] = __builtin_amdgcn_mfma_f32_16x16x32_bf16(af[m], bfr[n], acc[m][n], 0, 0, 0);
    }
    __syncthreads();
  }

  // ---- epilogue: bias + relu; C/D layout col=lane&15, row=(lane>>4)*4+j ----
  float lsum = 0.f;
  #pragma unroll
  for (int n = 0; n < 4; ++n) {
    const int col = n0 + ac + n * 16 + l15;
    const float bv = bias[col];
    #pragma unroll
    for (int m = 0; m < 4; ++m) {
      const int rbase = m0 + ar + m * 16 + l4 * 4;
      #pragma unroll
      for (int j = 0; j < 4; ++j) {
        float v = acc[m][n][j] + bv;
        v = v > 0.f ? v : 0.f;
        if (EPI == 0) {
          ((u16*)Cout)[(size_t)(rbase + j) * N + col] = f2bf(v);
        } else {
          ((float*)Cout)[(size_t)(rbase + j) * N + col] = v;
          lsum += v;
        }
      }
    }
  }
  if (EPI == 1) {
    #pragma unroll
    for (int off = 32; off > 0; off >>= 1) lsum += __shfl_down(lsum, off, 64);
    __shared__ float wred[4];
    if (lane == 0) wred[wid] = lsum;
    __syncthreads();
    if (tid == 0) atomicAdd(sum_acc, wred[0] + wred[1] + wred[2] + wred[3]);
  }
}

__global__ void cvt_bf16(const float* __restrict__ in, u16* __restrict__ out, size_t n) {
  size_t i = ((size_t)blockIdx.x * blockDim.x + threadIdx.x) * 8;
  const size_t stride = (size_t)gridDim.x * blockDim.x * 8;
  for (; i < n; i += stride) {
    const float4 a = *(const float4*)(in + i);
    const float4 b = *(const float4*)(in + i + 4);
    u16x8 o;
    o[0] = f2bf(a.x); o[1] = f2bf(a.y); o[2] = f2bf(a.z); o[3] = f2bf(a.w);
    o[4] = f2bf(b.x); o[5] = f2bf(b.y); o[6] = f2bf(b.z); o[7] = f2bf(b.w);
    *(u16x8*)(out + i) = o;
  }
}

__global__ void mask_thresh(const float* __restrict__ mask, const float* __restrict__ sumv,
                            float* __restrict__ out, size_t n) {
  const float thr = *sumv * (1.0f / (float)NROWS);
  size_t i = ((size_t)blockIdx.x * blockDim.x + threadIdx.x) * 4;
  const size_t stride = (size_t)gridDim.x * blockDim.x * 4;
  for (; i < n; i += stride) {
    const float4 m = *(const float4*)(mask + i);
    float4 o;
    o.x = m.x > thr ? 1.f : 0.f;
    o.y = m.y > thr ? 1.f : 0.f;
    o.z = m.z > thr ? 1.f : 0.f;
    o.w = m.w > thr ? 1.f : 0.f;
    *(float4*)(out + i) = o;
  }
}

extern "C" void kernel_launch(void* const* d_in, const int* in_sizes, int n_in,
                              void* d_out, int out_size, void* d_ws, size_t ws_size,
                              hipStream_t stream) {
  (void)in_sizes; (void)n_in; (void)out_size; (void)ws_size;
  const float* X  = (const float*)d_in[0];
  const float* Mk = (const float*)d_in[1];
  const float* W1 = (const float*)d_in[2];
  const float* b1 = (const float*)d_in[3];
  const float* W2 = (const float*)d_in[4];
  const float* b2 = (const float*)d_in[5];
  const float* W3 = (const float*)d_in[6];
  const float* b3 = (const float*)d_in[7];

  // workspace layout (peak ~325 MB)
  char* ws = (char*)d_ws;
  u16*   W1b  = (u16*)(ws);                    // 1 MB
  u16*   W2b  = (u16*)(ws + (1ull  << 20));    // 2 MB
  u16*   W3b  = (u16*)(ws + (3ull  << 20));    // 1 MB
  float* sumv = (float*)(ws + (4ull  << 20));  // 4 B
  u16*   Xb   = (u16*)(ws + (5ull  << 20));    // 64 MB  (CHUNK x 512 bf16)
  u16*   h1   = (u16*)(ws + (69ull << 20));    // 128 MB (CHUNK x 1024 bf16)
  u16*   h2   = (u16*)(ws + (197ull << 20));   // 128 MB

  hipMemsetAsync(sumv, 0, sizeof(float), stream);
  cvt_bf16<<<256, 256, 0, stream>>>(W1, W1b, (size_t)H1DIM * DIN);
  cvt_bf16<<<512, 256, 0, stream>>>(W2, W2b, (size_t)H2DIM * H1DIM);
  cvt_bf16<<<256, 256, 0, stream>>>(W3, W3b, (size_t)DOUT * H2DIM);

  float* out_mlp  = (float*)d_out;
  float* out_mask = out_mlp + (size_t)NROWS * DOUT;

  for (int c = 0; c < NROWS / CHUNK; ++c) {
    const float* xin = X + (size_t)c * CHUNK * DIN;
    cvt_bf16<<<4096, 256, 0, stream>>>(xin, Xb, (size_t)CHUNK * DIN);
    mlp_gemm<0><<<(CHUNK / 128) * (H1DIM / 128), 256, 0, stream>>>(
        Xb, W1b, b1, h1, nullptr, CHUNK, H1DIM, DIN);
    mlp_gemm<0><<<(CHUNK / 128) * (H2DIM / 128), 256, 0, stream>>>(
        h1, W2b, b2, h2, nullptr, CHUNK, H2DIM, H1DIM);
    mlp_gemm<1><<<(CHUNK / 128) * (DOUT / 128), 256, 0, stream>>>(
        h2, W3b, b3, out_mlp + (size_t)c * CHUNK * DOUT, sumv, CHUNK, DOUT, H2DIM);
  }
  mask_thresh<<<4096, 256, 0, stream>>>(Mk, sumv, out_mask, MASKN);
}